// Round 10
// baseline (140.571 us; speedup 1.0000x reference)
//
#include <hip/hip_runtime.h>
#include <hip/hip_bf16.h>

#define Q 8192
#define DF 384
#define DP 16
#define NDATA 40000
#define AUGK 32
#define QPRE_BLOCKS 512                      // 16 query rows each
#define DPRE_BLOCKS ((NDATA + 255) / 256)    // 157
#define NQBLK3 32                            // q-groups of 256 (4 waves x 64 rows)
#define NCHUNK 64                            // 32 x 64 = 2048 blocks = 8/CU exactly
#define SCH_C 126.95703125f                  // Schraudolph exp2 bias constant
#define P23 8388608.f                        // 2^23

typedef __attribute__((ext_vector_type(8))) short short8v;   // 8 bf16
typedef __attribute__((ext_vector_type(4))) float f32x4;

__device__ __forceinline__ unsigned short f2bf(float x) {   // RNE to bf16
    union { float f; unsigned int u; } c; c.f = x;
    unsigned int u = c.u;
    u += 0x7fff + ((u >> 16) & 1);
    return (unsigned short)(u >> 16);
}
__device__ __forceinline__ float bf2f(unsigned short h) {
    union { float f; unsigned int u; } c; c.u = ((unsigned int)h) << 16;
    return c.f;
}
__device__ __forceinline__ float i2f_bits(int i) {
    union { int i; float f; } c; c.i = i; return c.f;
}
__device__ __forceinline__ float fexp2(float x) {
#if __has_builtin(__builtin_amdgcn_exp2f)
    return __builtin_amdgcn_exp2f(x);
#else
    float r; asm volatile("v_exp_f32 %0, %1" : "=v"(r) : "v"(x)); return r;
#endif
}

// ---------------------------------------------------------------------------
// k_pre (fused): blocks [0,512): query projection (M2 = scale*sv.bw computed
// redundantly per block in LDS) -> cfb bf16 rows + qb; blocks [512,..):
// dataset -> dsb bf16 rows (coords + Schraudolph bias hi/lo in K slots 16/17).
// ---------------------------------------------------------------------------
__global__ __launch_bounds__(256) void k_pre(
    const float* __restrict__ feat, const float* __restrict__ ds,
    const float* __restrict__ mean, const float* __restrict__ sv,
    const float* __restrict__ bw, const float* __restrict__ maxlen_p,
    unsigned short* __restrict__ cfb, float* __restrict__ qb,
    unsigned short* __restrict__ dsb)
{
    int t = threadIdx.x;

    if (blockIdx.x >= QPRE_BLOCKS) {             // ---- dataset role ----
        int j = (int)(blockIdx.x - QPRE_BLOCKS) * 256 + t;
        if (j < NDATA) {
            const float4* r = (const float4*)(ds + (size_t)j * DP);
            unsigned int pk[8];
            float ss = 0.f;
#pragma unroll
            for (int q4 = 0; q4 < 4; ++q4) {
                float4 v = r[q4];
                unsigned short h0 = f2bf(v.x), h1 = f2bf(v.y);
                unsigned short h2 = f2bf(v.z), h3 = f2bf(v.w);
                float f0 = bf2f(h0), f1 = bf2f(h1), f2 = bf2f(h2), f3 = bf2f(h3);
                ss += f0 * f0 + f1 * f1 + f2 * f2 + f3 * f3;   // rounded values
                pk[q4 * 2 + 0] = (unsigned int)h0 | ((unsigned int)h1 << 16);
                pk[q4 * 2 + 1] = (unsigned int)h2 | ((unsigned int)h3 << 16);
            }
            float v = fmaf(ss, -0.72134752044f, SCH_C);  // C - 0.5*log2e*|d|^2
            unsigned short hi = f2bf(v);
            unsigned short lo = f2bf(v - bf2f(hi));
            uint4* dst = (uint4*)(dsb + (size_t)j * AUGK);
            dst[0] = make_uint4(pk[0], pk[1], pk[2], pk[3]);
            dst[1] = make_uint4(pk[4], pk[5], pk[6], pk[7]);
            dst[2] = make_uint4((unsigned int)hi | ((unsigned int)lo << 16), 0u, 0u, 0u);
            dst[3] = make_uint4(0u, 0u, 0u, 0u);
        }
        return;
    }

    // ---- query role: rows [blockIdx*16, +16) ----
    __shared__ __align__(16) float m2l[DF * 20];    // [384][20] padded
    __shared__ float bwl[256];
    __shared__ float red[256];
    __shared__ float cmps[16];
    __shared__ float ccl[16];

    bwl[t] = bw[t];
    {   // mean.sv partials: 16 slices x 16 k
        int k = t & 15, s = t >> 4;
        float a = 0.f;
        for (int d = s; d < DF; d += 16)
            a = fmaf(mean[d], sv[d * DP + k], a);
        red[t] = a;
    }
    __syncthreads();
    float scale = P23 * 1.4426950408889634f / (*maxlen_p);
    for (int d = t; d < DF; d += 256) {          // M2[d][j] = scale*(sv.bw)[d][j]
        const float4* s4 = (const float4*)(sv + (size_t)d * DP);
        float4 a0 = s4[0], a1 = s4[1], a2 = s4[2], a3 = s4[3];
        float svr[16] = {a0.x, a0.y, a0.z, a0.w, a1.x, a1.y, a1.z, a1.w,
                         a2.x, a2.y, a2.z, a2.w, a3.x, a3.y, a3.z, a3.w};
        float* md = m2l + d * 20;
#pragma unroll
        for (int j = 0; j < 16; ++j) {
            float m = 0.f;
#pragma unroll
            for (int k = 0; k < 16; ++k) m = fmaf(svr[k], bwl[k * 16 + j], m);
            md[j] = scale * m;
        }
    }
    if (t < 16) {                                // cmps[k] = (mean.sv)[k]
        float m = 0.f;
#pragma unroll
        for (int s = 0; s < 16; ++s) m += red[s * 16 + t];
        cmps[t] = m;
    }
    __syncthreads();
    if (t < 16) {                                // ccl[j] = scale*(cmps.bw)[j]
        float s = 0.f;
#pragma unroll
        for (int k = 0; k < 16; ++k) s = fmaf(cmps[k], bwl[k * 16 + t], s);
        ccl[t] = scale * s;
    }
    __syncthreads();

    int r = t >> 4, s = t & 15;
    int row = (int)blockIdx.x * 16 + r;
    float acc[16];
#pragma unroll
    for (int k = 0; k < 16; ++k) acc[k] = 0.f;
    const float* fr = feat + (size_t)row * DF;
#pragma unroll 4
    for (int c = 0; c < 24; ++c) {
        int d = s + (c << 4);
        float fv = fr[d];
        const float4* mr = (const float4*)(m2l + d * 20);
        float4 m0 = mr[0], m1 = mr[1], m2 = mr[2], m3 = mr[3];
        acc[0]  = fmaf(fv, m0.x, acc[0]);  acc[1]  = fmaf(fv, m0.y, acc[1]);
        acc[2]  = fmaf(fv, m0.z, acc[2]);  acc[3]  = fmaf(fv, m0.w, acc[3]);
        acc[4]  = fmaf(fv, m1.x, acc[4]);  acc[5]  = fmaf(fv, m1.y, acc[5]);
        acc[6]  = fmaf(fv, m1.z, acc[6]);  acc[7]  = fmaf(fv, m1.w, acc[7]);
        acc[8]  = fmaf(fv, m2.x, acc[8]);  acc[9]  = fmaf(fv, m2.y, acc[9]);
        acc[10] = fmaf(fv, m2.z, acc[10]); acc[11] = fmaf(fv, m2.w, acc[11]);
        acc[12] = fmaf(fv, m3.x, acc[12]); acc[13] = fmaf(fv, m3.y, acc[13]);
        acc[14] = fmaf(fv, m3.z, acc[14]); acc[15] = fmaf(fv, m3.w, acc[15]);
    }
#pragma unroll
    for (int k = 0; k < 16; ++k) {
        acc[k] += __shfl_xor(acc[k], 1);
        acc[k] += __shfl_xor(acc[k], 2);
        acc[k] += __shfl_xor(acc[k], 4);
        acc[k] += __shfl_xor(acc[k], 8);
    }
    if (s == 0) {
        unsigned int pk[16];
        unsigned short h[16];
        float s2 = 0.f;
#pragma unroll
        for (int k = 0; k < 16; ++k) {
            float f = acc[k] - ccl[k];           // 2^23 * log2e/ml * proj
            h[k] = f2bf(f);
            float fr2 = bf2f(h[k]) * (1.f / P23);
            s2 += fr2 * fr2;
        }
        qb[row] = -0.34657359028f * s2;          // -0.5*ln2*|Fs|^2  (base-2)
#pragma unroll
        for (int p = 0; p < 8; ++p)
            pk[p] = (unsigned int)h[2 * p] | ((unsigned int)h[2 * p + 1] << 16);
        pk[8] = 0x4B004B00u;                     // bf16 {2^23, 2^23}
#pragma unroll
        for (int p = 9; p < 16; ++p) pk[p] = 0u;
        uint4* dst = (uint4*)(cfb + (size_t)row * AUGK);
        dst[0] = make_uint4(pk[0], pk[1], pk[2], pk[3]);
        dst[1] = make_uint4(pk[4], pk[5], pk[6], pk[7]);
        dst[2] = make_uint4(pk[8], pk[9], pk[10], pk[11]);
        dst[3] = make_uint4(pk[12], pk[13], pk[14], pk[15]);
    }
}

// ---------------------------------------------------------------------------
// k3: proven-best R6 structure. Wave = 64 q-rows (4 A-frags); one 16-pt
// B-tile feeds 4 MFMA; Schraudolph epilogue (cvt+add); 2-deep B prefetch,
// pointer-bump. Grid = 32 qblk x 64 chunks = 2048 blocks = 8/CU exactly,
// __launch_bounds__(256,8) -> VGPR 32, 8 waves/SIMD. No LDS/barriers/fences.
// ---------------------------------------------------------------------------
#define COMPT(bf)                                                             \
    {                                                                         \
        f32x4 d0 = __builtin_amdgcn_mfma_f32_16x16x32_bf16(a0, bf, z, 0, 0, 0); \
        f32x4 d1 = __builtin_amdgcn_mfma_f32_16x16x32_bf16(a1, bf, z, 0, 0, 0); \
        f32x4 d2 = __builtin_amdgcn_mfma_f32_16x16x32_bf16(a2, bf, z, 0, 0, 0); \
        f32x4 d3 = __builtin_amdgcn_mfma_f32_16x16x32_bf16(a3, bf, z, 0, 0, 0); \
        _Pragma("unroll")                                                     \
        for (int r = 0; r < 4; ++r) {                                         \
            sacc[0][r] += i2f_bits((int)d0[r]);                               \
            sacc[1][r] += i2f_bits((int)d1[r]);                               \
            sacc[2][r] += i2f_bits((int)d2[r]);                               \
            sacc[3][r] += i2f_bits((int)d3[r]);                               \
        }                                                                     \
    }

__global__ __launch_bounds__(256, 8) void k3_main(
    const unsigned short* __restrict__ cfb, const unsigned short* __restrict__ dsb,
    float* __restrict__ partial)
{
    int t = threadIdx.x;
    int qblk = (int)blockIdx.x & (NQBLK3 - 1);
    int c    = (int)blockIdx.x >> 5;
    int w = t >> 6, l = t & 63;
    int qbase = qblk * 256 + w * 64;
    int kg = l >> 4, col = l & 15;

    // uneven split of 2500 tiles into 64 chunks: first 4 get 40, rest 39
    int start = c * 39 + min(c, 4);
    int ntile = 39 + (c < 4 ? 1 : 0);

    const short8v* ap = (const short8v*)(cfb + (size_t)(qbase + col) * AUGK + kg * 8);
    short8v a0 = ap[0];
    short8v a1 = ap[64];                         // +16 rows = 16*32/8 short8v
    short8v a2 = ap[128];
    short8v a3 = ap[192];

    const short8v* bp = (const short8v*)(dsb + ((size_t)(start * 16 + col) * AUGK) + kg * 8);

    float sacc[4][4] = {{0.f,0.f,0.f,0.f},{0.f,0.f,0.f,0.f},
                        {0.f,0.f,0.f,0.f},{0.f,0.f,0.f,0.f}};
    f32x4 z = {0.f, 0.f, 0.f, 0.f};

    int npair = ntile >> 1;                      // >= 19
    short8v bf0 = bp[0];
    short8v bf1 = bp[64];
    bp += 128;
    for (int p = 0; p + 1 < npair; ++p) {
        short8v n0 = bp[0];
        short8v n1 = bp[64];
        bp += 128;
        COMPT(bf0);
        COMPT(bf1);
        bf0 = n0; bf1 = n1;
    }
    COMPT(bf0);
    COMPT(bf1);
    if (ntile & 1) {
        short8v bl = bp[0];
        COMPT(bl);
    }

#pragma unroll
    for (int o = 1; o < 16; o <<= 1)
#pragma unroll
        for (int tt = 0; tt < 4; ++tt)
#pragma unroll
            for (int r = 0; r < 4; ++r)
                sacc[tt][r] += __shfl_xor(sacc[tt][r], o);

    if (col == 0) {
        float* dst = partial + (size_t)c * Q + qbase;
#pragma unroll
        for (int tt = 0; tt < 4; ++tt)
#pragma unroll
            for (int r = 0; r < 4; ++r)
                dst[tt * 16 + kg * 4 + r] = sacc[tt][r];
    }
}

// ---------------------------------------------------------------------------
// k4: 8-way parallel chunk reduce per query + tail
// ---------------------------------------------------------------------------
__global__ __launch_bounds__(256) void k4_final(
    const float* __restrict__ partial, const float* __restrict__ qb,
    const float* __restrict__ norm_p, float* __restrict__ out)
{
    __shared__ float l2[8][33];
    int t = threadIdx.x;
    int ql = t & 31, sl = t >> 5;
    int q = (int)blockIdx.x * 32 + ql;
    float a = 0.f;
    for (int cc = sl; cc < NCHUNK; cc += 8) a += partial[(size_t)cc * Q + q];
    l2[sl][ql] = a;
    __syncthreads();
    if (t < 32) {
        int qq = (int)blockIdx.x * 32 + t;
        float s = 0.f;
#pragma unroll
        for (int s8 = 0; s8 < 8; ++s8) s += l2[s8][t];
        float est = (*norm_p) * (1.0f / (float)NDATA) * fexp2(qb[qq]) * s;
        float score = logf(est + 1e-38f);
        out[qq] = 1.0f / (1.0f + expf(0.05f * (score - 12.0f)));
    }
}

extern "C" void kernel_launch(void* const* d_in, const int* in_sizes, int n_in,
                              void* d_out, int out_size, void* d_ws, size_t ws_size,
                              hipStream_t stream) {
    const float* features = (const float*)d_in[0];
    const float* pca_mean = (const float*)d_in[1];
    const float* sv       = (const float*)d_in[2];
    const float* maxlen   = (const float*)d_in[3];
    const float* bw       = (const float*)d_in[4];
    const float* dataset  = (const float*)d_in[5];
    const float* norm     = (const float*)d_in[6];
    float* out = (float*)d_out;

    char* ws = (char*)d_ws;
    unsigned short* cfb = (unsigned short*)(ws);                 // 524288 B
    unsigned short* dsb = (unsigned short*)(ws + 524288);        // 2560000 B
    float* qb = (float*)(ws + 524288 + 2560000 + 4096);          // 32768 B
    float* partial = (float*)(ws + 524288 + 2560000 + 4096 + 32768);

    k_pre<<<QPRE_BLOCKS + DPRE_BLOCKS, 256, 0, stream>>>(
        features, dataset, pca_mean, sv, bw, maxlen, cfb, qb, dsb);
    k3_main<<<NQBLK3 * NCHUNK, 256, 0, stream>>>(cfb, dsb, partial);
    k4_final<<<Q / 32, 256, 0, stream>>>(partial, qb, norm, out);
}

// Round 11
// 117.568 us; speedup vs baseline: 1.1957x; 1.1957x over previous
//
#include <hip/hip_runtime.h>
#include <hip/hip_bf16.h>

#define Q 8192
#define DF 384
#define DP 16
#define NDATA 40000
#define AUGK 32
#define QPRE_BLOCKS 512                      // 16 query rows each
#define DPRE_BLOCKS ((NDATA + 255) / 256)    // 157
#define NQBLK3 32                            // q-groups of 256 (4 waves x 64 rows)
#define NCHUNK 64                            // 64 chunks x 32 qblks = 2048 blocks
#define SCH_C 126.95703125f                  // Schraudolph exp2 bias constant
#define P23 8388608.f                        // 2^23

typedef __attribute__((ext_vector_type(8))) short short8v;   // 8 bf16
typedef __attribute__((ext_vector_type(4))) float f32x4;

__device__ __forceinline__ unsigned short f2bf(float x) {   // RNE to bf16
    union { float f; unsigned int u; } c; c.f = x;
    unsigned int u = c.u;
    u += 0x7fff + ((u >> 16) & 1);
    return (unsigned short)(u >> 16);
}
__device__ __forceinline__ float bf2f(unsigned short h) {
    union { float f; unsigned int u; } c; c.u = ((unsigned int)h) << 16;
    return c.f;
}
__device__ __forceinline__ float i2f_bits(int i) {
    union { int i; float f; } c; c.i = i; return c.f;
}
__device__ __forceinline__ float fexp2(float x) {
#if __has_builtin(__builtin_amdgcn_exp2f)
    return __builtin_amdgcn_exp2f(x);
#else
    float r; asm volatile("v_exp_f32 %0, %1" : "=v"(r) : "v"(x)); return r;
#endif
}

// ---------------------------------------------------------------------------
// k_mm (1 block, 384 threads): M2[d][k] = 2^23*log2e/ml * (sv.bw)[d][k]  (fp32)
//                              cc[k]    = 2^23*log2e/ml * ((mean.sv).bw)[k]
// ---------------------------------------------------------------------------
__global__ __launch_bounds__(384) void k_mm(
    const float* __restrict__ mean, const float* __restrict__ sv,
    const float* __restrict__ bw, const float* __restrict__ maxlen_p,
    float* __restrict__ M2, float* __restrict__ cc)
{
    __shared__ float bwl[256];
    __shared__ float red[384];
    __shared__ float cmps[16];
    int t = threadIdx.x;
    if (t < 256) bwl[t] = bw[t];
    {   // mean.sv partials: 24 slices x 16 k
        int k = t & 15, s = t >> 4;
        float a = 0.f;
        for (int d = s; d < DF; d += 24)
            a = fmaf(mean[d], sv[d * DP + k], a);
        red[t] = a;
    }
    __syncthreads();
    float scale = P23 * 1.4426950408889634f / (*maxlen_p);
    {   // M2 row d = t
        const float4* s4 = (const float4*)(sv + (size_t)t * DP);
        float4 a0 = s4[0], a1 = s4[1], a2 = s4[2], a3 = s4[3];
        float svr[16] = {a0.x, a0.y, a0.z, a0.w, a1.x, a1.y, a1.z, a1.w,
                         a2.x, a2.y, a2.z, a2.w, a3.x, a3.y, a3.z, a3.w};
        float mrow[16];
#pragma unroll
        for (int j = 0; j < 16; ++j) {
            float m = 0.f;
#pragma unroll
            for (int k = 0; k < 16; ++k) m = fmaf(svr[k], bwl[k * 16 + j], m);
            mrow[j] = scale * m;
        }
        float4* md = (float4*)(M2 + (size_t)t * DP);
        md[0] = make_float4(mrow[0], mrow[1], mrow[2], mrow[3]);
        md[1] = make_float4(mrow[4], mrow[5], mrow[6], mrow[7]);
        md[2] = make_float4(mrow[8], mrow[9], mrow[10], mrow[11]);
        md[3] = make_float4(mrow[12], mrow[13], mrow[14], mrow[15]);
    }
    if (t < 16) {
        float m = 0.f;
        for (int s = 0; s < 24; ++s) m += red[s * 16 + t];
        cmps[t] = m;
    }
    __syncthreads();
    if (t < 16) {
        float s = 0.f;
#pragma unroll
        for (int k = 0; k < 16; ++k) s = fmaf(cmps[k], bwl[k * 16 + t], s);
        cc[t] = scale * s;
    }
}

// ---------------------------------------------------------------------------
// k_pre:
//  blocks [0,512):  16 query rows -> cfb[q][32] bf16: slots 0-15 = 2^23-scaled
//                   coords, 16/17 = 2^23; qb[q]
//  blocks [512,..): dataset -> dsb[j][32] bf16: coords + v=(C-0.72135|d|^2) hi/lo
// ---------------------------------------------------------------------------
__global__ __launch_bounds__(256) void k_pre(
    const float* __restrict__ feat, const float* __restrict__ ds,
    const float* __restrict__ M2, const float* __restrict__ cc,
    unsigned short* __restrict__ cfb, float* __restrict__ qb,
    unsigned short* __restrict__ dsb)
{
    int t = threadIdx.x;

    if (blockIdx.x >= QPRE_BLOCKS) {             // ---- dataset role ----
        int j = (int)(blockIdx.x - QPRE_BLOCKS) * 256 + t;
        if (j < NDATA) {
            const float4* r = (const float4*)(ds + (size_t)j * DP);
            unsigned int pk[8];
            float ss = 0.f;
#pragma unroll
            for (int q4 = 0; q4 < 4; ++q4) {
                float4 v = r[q4];
                unsigned short h0 = f2bf(v.x), h1 = f2bf(v.y);
                unsigned short h2 = f2bf(v.z), h3 = f2bf(v.w);
                float f0 = bf2f(h0), f1 = bf2f(h1), f2 = bf2f(h2), f3 = bf2f(h3);
                ss += f0 * f0 + f1 * f1 + f2 * f2 + f3 * f3;   // rounded values
                pk[q4 * 2 + 0] = (unsigned int)h0 | ((unsigned int)h1 << 16);
                pk[q4 * 2 + 1] = (unsigned int)h2 | ((unsigned int)h3 << 16);
            }
            float v = fmaf(ss, -0.72134752044f, SCH_C);  // C - 0.5*log2e*|d|^2
            unsigned short hi = f2bf(v);
            unsigned short lo = f2bf(v - bf2f(hi));
            uint4* dst = (uint4*)(dsb + (size_t)j * AUGK);
            dst[0] = make_uint4(pk[0], pk[1], pk[2], pk[3]);
            dst[1] = make_uint4(pk[4], pk[5], pk[6], pk[7]);
            dst[2] = make_uint4((unsigned int)hi | ((unsigned int)lo << 16), 0u, 0u, 0u);
            dst[3] = make_uint4(0u, 0u, 0u, 0u);
        }
        return;
    }

    // ---- query role: rows [blockIdx*16, +16) ----
    __shared__ __align__(16) float m2l[DF * 20];    // [384][20] pad: 2-way max
    __shared__ float ccl[16];
    const float4* m2g = (const float4*)M2;
#pragma unroll
    for (int it = 0; it < 6; ++it) {
        int i = it * 256 + t;
        int d = i >> 2, qq = i & 3;
        *(float4*)(m2l + d * 20 + qq * 4) = m2g[i];
    }
    if (t < 16) ccl[t] = cc[t];
    __syncthreads();

    int r = t >> 4, s = t & 15;
    int row = (int)blockIdx.x * 16 + r;
    float acc[16];
#pragma unroll
    for (int k = 0; k < 16; ++k) acc[k] = 0.f;
    const float* fr = feat + (size_t)row * DF;
#pragma unroll 4
    for (int c = 0; c < 24; ++c) {
        int d = s + (c << 4);
        float fv = fr[d];
        const float4* mr = (const float4*)(m2l + d * 20);
        float4 m0 = mr[0], m1 = mr[1], m2 = mr[2], m3 = mr[3];
        acc[0]  = fmaf(fv, m0.x, acc[0]);  acc[1]  = fmaf(fv, m0.y, acc[1]);
        acc[2]  = fmaf(fv, m0.z, acc[2]);  acc[3]  = fmaf(fv, m0.w, acc[3]);
        acc[4]  = fmaf(fv, m1.x, acc[4]);  acc[5]  = fmaf(fv, m1.y, acc[5]);
        acc[6]  = fmaf(fv, m1.z, acc[6]);  acc[7]  = fmaf(fv, m1.w, acc[7]);
        acc[8]  = fmaf(fv, m2.x, acc[8]);  acc[9]  = fmaf(fv, m2.y, acc[9]);
        acc[10] = fmaf(fv, m2.z, acc[10]); acc[11] = fmaf(fv, m2.w, acc[11]);
        acc[12] = fmaf(fv, m3.x, acc[12]); acc[13] = fmaf(fv, m3.y, acc[13]);
        acc[14] = fmaf(fv, m3.z, acc[14]); acc[15] = fmaf(fv, m3.w, acc[15]);
    }
#pragma unroll
    for (int k = 0; k < 16; ++k) {
        acc[k] += __shfl_xor(acc[k], 1);
        acc[k] += __shfl_xor(acc[k], 2);
        acc[k] += __shfl_xor(acc[k], 4);
        acc[k] += __shfl_xor(acc[k], 8);
    }
    if (s == 0) {
        unsigned int pk[16];
        unsigned short h[16];
        float s2 = 0.f;
#pragma unroll
        for (int k = 0; k < 16; ++k) {
            float f = acc[k] - ccl[k];           // 2^23 * log2e/ml * proj
            h[k] = f2bf(f);
            float fr2 = bf2f(h[k]) * (1.f / P23);
            s2 += fr2 * fr2;
        }
        qb[row] = -0.34657359028f * s2;          // -0.5*ln2*|Fs|^2
#pragma unroll
        for (int p = 0; p < 8; ++p)
            pk[p] = (unsigned int)h[2 * p] | ((unsigned int)h[2 * p + 1] << 16);
        pk[8] = 0x4B004B00u;                     // bf16 {2^23, 2^23}
#pragma unroll
        for (int p = 9; p < 16; ++p) pk[p] = 0u;
        uint4* dst = (uint4*)(cfb + (size_t)row * AUGK);
        dst[0] = make_uint4(pk[0], pk[1], pk[2], pk[3]);
        dst[1] = make_uint4(pk[4], pk[5], pk[6], pk[7]);
        dst[2] = make_uint4(pk[8], pk[9], pk[10], pk[11]);
        dst[3] = make_uint4(pk[12], pk[13], pk[14], pk[15]);
    }
}

// ---------------------------------------------------------------------------
// k3: wave = 64 q-rows (4 A-frags); 16-pt B-tile shared by 4 MFMA; Schraudolph
// epilogue (cvt+add). 2-deep B prefetch. Grid = 64 chunks x 32 qblks = 2048
// blocks = exactly 8 blocks/CU. Non-atomic partial[] store.
// ---------------------------------------------------------------------------
#define COMPT(bf)                                                             \
    {                                                                         \
        f32x4 d0 = __builtin_amdgcn_mfma_f32_16x16x32_bf16(a0, bf, z, 0, 0, 0); \
        f32x4 d1 = __builtin_amdgcn_mfma_f32_16x16x32_bf16(a1, bf, z, 0, 0, 0); \
        f32x4 d2 = __builtin_amdgcn_mfma_f32_16x16x32_bf16(a2, bf, z, 0, 0, 0); \
        f32x4 d3 = __builtin_amdgcn_mfma_f32_16x16x32_bf16(a3, bf, z, 0, 0, 0); \
        _Pragma("unroll")                                                     \
        for (int r = 0; r < 4; ++r) {                                         \
            sacc[0][r] += i2f_bits((int)d0[r]);                               \
            sacc[1][r] += i2f_bits((int)d1[r]);                               \
            sacc[2][r] += i2f_bits((int)d2[r]);                               \
            sacc[3][r] += i2f_bits((int)d3[r]);                               \
        }                                                                     \
    }

__global__ __launch_bounds__(256, 8) void k3_main(
    const unsigned short* __restrict__ cfb, const unsigned short* __restrict__ dsb,
    float* __restrict__ partial)
{
    int t = threadIdx.x;
    int qblk = (int)blockIdx.x & (NQBLK3 - 1);
    int c    = (int)blockIdx.x >> 5;
    int w = t >> 6, l = t & 63;
    int qbase = qblk * 256 + w * 64;
    int kg = l >> 4, col = l & 15;

    // uneven split of 2500 tiles into 64 chunks: first 4 get 40, rest 39
    int start = c * 39 + min(c, 4);
    int ntile = 39 + (c < 4 ? 1 : 0);
    int j0 = start * 16;

    const short8v* ap = (const short8v*)(cfb + (size_t)(qbase + col) * AUGK + kg * 8);
    short8v a0 = ap[0];
    short8v a1 = ap[64];                         // +16 rows
    short8v a2 = ap[128];
    short8v a3 = ap[192];

    const short8v* bp = (const short8v*)(dsb + (size_t)(j0 + col) * AUGK + kg * 8);

    float sacc[4][4] = {{0.f,0.f,0.f,0.f},{0.f,0.f,0.f,0.f},
                        {0.f,0.f,0.f,0.f},{0.f,0.f,0.f,0.f}};
    f32x4 z = {0.f, 0.f, 0.f, 0.f};

    int npair = ntile >> 1;                      // >= 19
    short8v bf0 = bp[0];
    short8v bf1 = bp[64];
    for (int p = 0; p + 1 < npair; ++p) {
        short8v n0 = bp[(size_t)(2 * p + 2) * 64];
        short8v n1 = bp[(size_t)(2 * p + 3) * 64];
        COMPT(bf0);
        COMPT(bf1);
        bf0 = n0; bf1 = n1;
    }
    COMPT(bf0);
    COMPT(bf1);
    if (ntile & 1) {
        short8v bl = bp[(size_t)(ntile - 1) * 64];
        COMPT(bl);
    }

#pragma unroll
    for (int o = 1; o < 16; o <<= 1)
#pragma unroll
        for (int tt = 0; tt < 4; ++tt)
#pragma unroll
            for (int r = 0; r < 4; ++r)
                sacc[tt][r] += __shfl_xor(sacc[tt][r], o);

    if (col == 0) {
        float* dst = partial + (size_t)c * Q + qbase;
#pragma unroll
        for (int tt = 0; tt < 4; ++tt)
#pragma unroll
            for (int r = 0; r < 4; ++r)
                dst[tt * 16 + kg * 4 + r] = sacc[tt][r];
    }
}

// ---------------------------------------------------------------------------
// k4: 8-way parallel chunk reduce per query + tail
// ---------------------------------------------------------------------------
__global__ __launch_bounds__(256) void k4_final(
    const float* __restrict__ partial, const float* __restrict__ qb,
    const float* __restrict__ norm_p, float* __restrict__ out)
{
    __shared__ float l2[8][33];
    int t = threadIdx.x;
    int ql = t & 31, sl = t >> 5;
    int q = (int)blockIdx.x * 32 + ql;
    float a = 0.f;
    for (int cc = sl; cc < NCHUNK; cc += 8) a += partial[(size_t)cc * Q + q];
    l2[sl][ql] = a;
    __syncthreads();
    if (t < 32) {
        int qq = (int)blockIdx.x * 32 + t;
        float s = 0.f;
#pragma unroll
        for (int s8 = 0; s8 < 8; ++s8) s += l2[s8][t];
        float est = (*norm_p) * (1.0f / (float)NDATA) * fexp2(qb[qq]) * s;
        float score = logf(est + 1e-38f);
        out[qq] = 1.0f / (1.0f + expf(0.05f * (score - 12.0f)));
    }
}

extern "C" void kernel_launch(void* const* d_in, const int* in_sizes, int n_in,
                              void* d_out, int out_size, void* d_ws, size_t ws_size,
                              hipStream_t stream) {
    const float* features = (const float*)d_in[0];
    const float* pca_mean = (const float*)d_in[1];
    const float* sv       = (const float*)d_in[2];
    const float* maxlen   = (const float*)d_in[3];
    const float* bw       = (const float*)d_in[4];
    const float* dataset  = (const float*)d_in[5];
    const float* norm     = (const float*)d_in[6];
    float* out = (float*)d_out;

    char* ws = (char*)d_ws;
    unsigned short* cfb = (unsigned short*)(ws);                 // 524288 B
    unsigned short* dsb = (unsigned short*)(ws + 524288);        // 2560000 B
    float* qb = (float*)(ws + 524288 + 2560000);                 // 32768 B
    float* M2 = (float*)(ws + 524288 + 2560000 + 32768);         // 24576 B
    float* cc = (float*)(ws + 524288 + 2560000 + 32768 + 24576); // 256 B
    float* partial = (float*)(ws + 524288 + 2560000 + 32768 + 24576 + 256);

    k_mm<<<1, 384, 0, stream>>>(pca_mean, sv, bw, maxlen, M2, cc);
    k_pre<<<QPRE_BLOCKS + DPRE_BLOCKS, 256, 0, stream>>>(
        features, dataset, M2, cc, cfb, qb, dsb);
    k3_main<<<NQBLK3 * NCHUNK, 256, 0, stream>>>(cfb, dsb, partial);
    k4_final<<<Q / 32, 256, 0, stream>>>(partial, qb, norm, out);
}